// Round 9
// baseline (141.254 us; speedup 1.0000x reference)
//
#include <hip/hip_runtime.h>
#include <math.h>

#define B_SZ 16384
#define D_DIM 128
#define A_SZ 8192
#define K_SZ 64
#define L2_REG_F 0.25f
#define GRID_BLKS 1024        // 4 blocks/CU x 256 CUs: exactly co-resident
#define GROUPS 32             // hierarchical barrier: 32 groups x 32 blocks
#define BLKS_PER_GROUP 32
#define CNT_STRIDE 32         // uints between counters (128 B; separate lines)

typedef float vfloat2 __attribute__((ext_vector_type(2)));

__device__ __forceinline__ float wave_reduce_sum(float v) {
    #pragma unroll
    for (int off = 32; off > 0; off >>= 1)
        v += __shfl_xor(v, off, 64);
    return v;
}

__device__ __forceinline__ float wave_reduce_max(float v) {
    #pragma unroll
    for (int off = 32; off > 0; off >>= 1)
        v = fmaxf(v, __shfl_xor(v, off, 64));
    return v;
}

__device__ __forceinline__ void dequant16(uint4 q, float4& o0, float4& o1,
                                          float4& o2, float4& o3) {
    vfloat2 f0 = __builtin_amdgcn_cvt_pk_f32_fp8(q.x, false);
    vfloat2 f1 = __builtin_amdgcn_cvt_pk_f32_fp8(q.x, true);
    vfloat2 f2 = __builtin_amdgcn_cvt_pk_f32_fp8(q.y, false);
    vfloat2 f3 = __builtin_amdgcn_cvt_pk_f32_fp8(q.y, true);
    vfloat2 f4 = __builtin_amdgcn_cvt_pk_f32_fp8(q.z, false);
    vfloat2 f5 = __builtin_amdgcn_cvt_pk_f32_fp8(q.z, true);
    vfloat2 f6 = __builtin_amdgcn_cvt_pk_f32_fp8(q.w, false);
    vfloat2 f7 = __builtin_amdgcn_cvt_pk_f32_fp8(q.w, true);
    o0 = make_float4(f0.x, f0.y, f1.x, f1.y);
    o1 = make_float4(f2.x, f2.y, f3.x, f3.y);
    o2 = make_float4(f4.x, f4.y, f5.x, f5.y);
    o3 = make_float4(f6.x, f6.y, f7.x, f7.y);
}

__device__ __forceinline__ float dot4(float4 a, float4 b) {
    return a.x * b.x + a.y * b.y + a.z * b.z + a.w * b.w;
}

// Fused single kernel with manual hierarchical grid barrier.
// cnt layout (uints, stride CNT_STRIDE): [0..31]*S group counters (bar1),
// [32]*S root1, [33..64]*S group counters (bar2), [65]*S root2.
__global__ __launch_bounds__(256, 4) void fused_kernel(
    const float* __restrict__ embed,
    const int* __restrict__ anc_ind,
    const int* __restrict__ pos_ind,
    const int* __restrict__ neg_ind,
    unsigned char* __restrict__ tab,      // 2 MB fp8 table, row stride 128 B
    float* __restrict__ partial,          // GRID_BLKS floats
    unsigned* __restrict__ cnt,           // barrier counters (pre-zeroed)
    float* __restrict__ out) {
    __shared__ float red[4];
    __shared__ int is_final;
    const int wave = threadIdx.x >> 6;
    const int lane = threadIdx.x & 63;
    const int blk  = blockIdx.x;
    const int w    = blk * 4 + wave;      // 0..4095

    // ---- phase 1: convert 4 rows/wave (16 lanes per row, 8 elems/lane) ----
    float acc_l2 = 0.f;
    {
        const int sub = lane >> 4;        // row within wave 0..3
        const int j   = lane & 15;        // 8-elem slot within row
        const int row = w * 4 + sub;      // 4096 waves x 4 = 16384 rows, exact
        const float4* rp = (const float4*)(embed + (size_t)row * D_DIM + j * 8);
        float4 va = rp[0], vb = rp[1];
        float ss = dot4(va, va) + dot4(vb, vb);
        ss += __shfl_xor(ss, 1, 64);      // group-of-16 reduce
        ss += __shfl_xor(ss, 2, 64);
        ss += __shfl_xor(ss, 4, 64);
        ss += __shfl_xor(ss, 8, 64);
        if (j == 0) acc_l2 = sqrtf(ss);   // exact fp32 norm, 1 lane per row
        unsigned u0 = __builtin_amdgcn_cvt_pk_fp8_f32(va.x, va.y, 0, false);
        u0 = __builtin_amdgcn_cvt_pk_fp8_f32(va.z, va.w, u0, true);
        unsigned u1 = __builtin_amdgcn_cvt_pk_fp8_f32(vb.x, vb.y, 0, false);
        u1 = __builtin_amdgcn_cvt_pk_fp8_f32(vb.z, vb.w, u1, true);
        ((uint2*)(tab + (size_t)row * D_DIM))[j] = make_uint2(u0, u1);
    }

    // ---- grid barrier 1: table written + device-visible before gathers ----
    __syncthreads();
    if (threadIdx.x == 0) {
        __threadfence();                  // release: L2 writeback (agent scope)
        unsigned* gc   = cnt + (blk >> 5) * CNT_STRIDE;
        unsigned* root = cnt + GROUPS * CNT_STRIDE;
        if (atomicAdd(gc, 1u) == BLKS_PER_GROUP - 1)
            atomicAdd(root, 1u);          // one root increment per group
        long t = 0;
        while (__hip_atomic_load(root, __ATOMIC_RELAXED,
                                 __HIP_MEMORY_SCOPE_AGENT) < GROUPS) {
            __builtin_amdgcn_s_sleep(8);
            if (++t > (1L << 24)) break;  // safety valve: fail, never hang
        }
        __threadfence();                  // acquire: L2 invalidate
    }
    __syncthreads();

    // ---- phase 2: 2 anchors per wave, 8 lanes cooperate per negative row ----
    const int g = lane >> 3;   // row-in-pass 0..7
    const int c = lane & 7;    // 16B chunk 0..7 within a 128B row
    float acc_np = 0.f;
    #pragma unroll
    for (int t = 0; t < 2; ++t) {
        const int i  = w * 2 + t;         // anchor id 0..8191, exact
        const int ai = anc_ind[i];
        const int pi = pos_ind[i];
        const int nid_all = neg_ind[(size_t)i * K_SZ + lane];  // coalesced

        uint4 ua4 = ((const uint4*)(tab + (size_t)ai * D_DIM))[c];
        uint4 up4 = ((const uint4*)(tab + (size_t)pi * D_DIM))[c];

        int nidx[8];
        #pragma unroll
        for (int p = 0; p < 8; ++p)
            nidx[p] = __shfl(nid_all, p * 8 + g, 64);

        uint4 q[8];                       // all 8 gathers in flight
        #pragma unroll
        for (int p = 0; p < 8; ++p)
            q[p] = ((const uint4*)(tab + (size_t)nidx[p] * D_DIM))[c];

        float4 A0, A1, A2, A3;
        dequant16(ua4, A0, A1, A2, A3);
        float4 P0, P1, P2, P3;
        dequant16(up4, P0, P1, P2, P3);
        float ap = dot4(A0, P0) + dot4(A1, P1) + dot4(A2, P2) + dot4(A3, P3);
        ap += __shfl_xor(ap, 1, 64);
        ap += __shfl_xor(ap, 2, 64);
        ap += __shfl_xor(ap, 4, 64);

        float inner = 0.f;
        #pragma unroll
        for (int p = 0; p < 8; ++p) {
            float4 N0, N1, N2, N3;
            dequant16(q[p], N0, N1, N2, N3);
            float s = dot4(A0, N0) + dot4(A1, N1) + dot4(A2, N2) + dot4(A3, N3);
            s += __shfl_xor(s, 1, 64);
            s += __shfl_xor(s, 2, 64);
            s += __shfl_xor(s, 4, 64);
            if (c == p) inner = s;        // lane keeps negative (l&7)*8+(l>>3)
        }
        inner -= ap;                      // permutation: LSE-invariant

        float m  = wave_reduce_max(inner);
        float se = wave_reduce_sum(__expf(inner - m));
        float lse = m + __logf(se);
        acc_np += (lse > 0.f) ? lse + log1pf(__expf(-lse)) : log1pf(__expf(lse));
    }

    // ---- phase 3: block partial + last-arriver finalize ----
    float contrib = acc_l2 * (L2_REG_F / (float)B_SZ)   // 4 lanes/wave nonzero
                  + ((lane == 0) ? acc_np * (1.0f / (float)A_SZ) : 0.f);
    contrib = wave_reduce_sum(contrib);
    if (lane == 0) red[wave] = contrib;
    if (threadIdx.x == 0) is_final = 0;
    __syncthreads();
    if (threadIdx.x == 0) {
        partial[blk] = red[0] + red[1] + red[2] + red[3];
        __threadfence();                  // release partial (L2 wb)
        unsigned* gc2   = cnt + (GROUPS + 1 + (blk >> 5)) * CNT_STRIDE;
        unsigned* root2 = cnt + (2 * GROUPS + 1) * CNT_STRIDE;
        if (atomicAdd(gc2, 1u) == BLKS_PER_GROUP - 1)
            if (atomicAdd(root2, 1u) == GROUPS - 1)
                is_final = 1;             // this block saw all partials done
    }
    __syncthreads();
    if (is_final) {
        if (threadIdx.x == 0) __threadfence();  // acquire: L2 invalidate
        __syncthreads();
        float v = partial[threadIdx.x]       + partial[threadIdx.x + 256]
                + partial[threadIdx.x + 512] + partial[threadIdx.x + 768];
        v = wave_reduce_sum(v);
        if (lane == 0) red[wave] = v;
        __syncthreads();
        if (threadIdx.x == 0)
            out[0] = red[0] + red[1] + red[2] + red[3];
    }
}

// ---- fp32 fallback (only if ws can't hold table+counters) ----
__global__ __launch_bounds__(256) void f32_kernel(const float* __restrict__ embed,
                                                  const int* __restrict__ anc_ind,
                                                  const int* __restrict__ pos_ind,
                                                  const int* __restrict__ neg_ind,
                                                  float* __restrict__ partial) {
    __shared__ __align__(16) float a_lds[4][D_DIM];
    __shared__ float red[4];
    const int wave = threadIdx.x >> 6;
    const int lane = threadIdx.x & 63;
    const int gw   = blockIdx.x * 4 + wave;

    float acc_l2 = 0.f;
    #pragma unroll
    for (int r = 0; r < 2; ++r) {
        const int row = gw * 2 + r;
        const float2* rr = (const float2*)(embed + (size_t)row * D_DIM);
        float2 v = rr[lane];
        acc_l2 += sqrtf(wave_reduce_sum(v.x * v.x + v.y * v.y));
    }
    const int i  = gw;
    const int ai = anc_ind[i];
    const int pi = pos_ind[i];
    const int ni = neg_ind[(size_t)i * K_SZ + lane];
    const float2* ar = (const float2*)(embed + (size_t)ai * D_DIM);
    const float2* pr = (const float2*)(embed + (size_t)pi * D_DIM);
    float2 a2 = ar[lane];
    float2 p2 = pr[lane];
    a_lds[wave][2 * lane]     = a2.x;
    a_lds[wave][2 * lane + 1] = a2.y;
    float ap = wave_reduce_sum(a2.x * p2.x + a2.y * p2.y);
    const float4* nr = (const float4*)(embed + (size_t)ni * D_DIM);
    const float4* al = (const float4*)a_lds[wave];
    float s0 = 0.f, s1 = 0.f, s2 = 0.f, s3 = 0.f;
    #pragma unroll
    for (int j = 0; j < D_DIM / 4; j += 4) {
        float4 n0 = nr[j], n1 = nr[j + 1], n2 = nr[j + 2], n3 = nr[j + 3];
        float4 a0 = al[j], a1 = al[j + 1], a2v = al[j + 2], a3 = al[j + 3];
        s0 += dot4(a0, n0); s1 += dot4(a1, n1);
        s2 += dot4(a2v, n2); s3 += dot4(a3, n3);
    }
    float inner = (s0 + s1) + (s2 + s3) - ap;
    float m  = wave_reduce_max(inner);
    float se = wave_reduce_sum(__expf(inner - m));
    float lse = m + __logf(se);
    float per = (lse > 0.f) ? lse + log1pf(__expf(-lse)) : log1pf(__expf(lse));
    float combined = per * (1.0f / (float)A_SZ) + acc_l2 * (L2_REG_F / (float)B_SZ);
    if (lane == 0) red[wave] = combined;
    __syncthreads();
    if (threadIdx.x == 0)
        partial[blockIdx.x] = red[0] + red[1] + red[2] + red[3];
}

__global__ __launch_bounds__(256) void finalize_kernel(const float* __restrict__ partial,
                                                       int n, float* __restrict__ out) {
    __shared__ float red[4];
    const int wave = threadIdx.x >> 6;
    const int lane = threadIdx.x & 63;
    float v = 0.f;
    for (int j = threadIdx.x; j < n; j += 256) v += partial[j];
    v = wave_reduce_sum(v);
    if (lane == 0) red[wave] = v;
    __syncthreads();
    if (threadIdx.x == 0)
        out[0] = red[0] + red[1] + red[2] + red[3];
}

extern "C" void kernel_launch(void* const* d_in, const int* in_sizes, int n_in,
                              void* d_out, int out_size, void* d_ws, size_t ws_size,
                              hipStream_t stream) {
    const float* embed = (const float*)d_in[0];
    const int*   anc   = (const int*)d_in[1];
    const int*   pos   = (const int*)d_in[2];
    const int*   neg   = (const int*)d_in[3];
    float* out = (float*)d_out;

    const size_t tab_bytes  = (size_t)B_SZ * D_DIM;            // 2 MB fp8
    const size_t part_bytes = GRID_BLKS * sizeof(float);
    const size_t cnt_bytes  = (size_t)(2 * GROUPS + 2) * CNT_STRIDE * sizeof(unsigned);
    const size_t need = tab_bytes + part_bytes + cnt_bytes;

    if (ws_size >= need) {
        unsigned char* tab = (unsigned char*)d_ws;
        float* partial = (float*)(tab + tab_bytes);
        unsigned* cnt  = (unsigned*)((char*)partial + part_bytes);
        hipMemsetAsync(cnt, 0, cnt_bytes, stream);
        fused_kernel<<<GRID_BLKS, 256, 0, stream>>>(embed, anc, pos, neg,
                                                    tab, partial, cnt, out);
    } else {
        float* partial = (float*)d_ws;
        f32_kernel<<<2048, 256, 0, stream>>>(embed, anc, pos, neg, partial);
        finalize_kernel<<<1, 256, 0, stream>>>(partial, 2048, out);
    }
}

// Round 10
// 111.735 us; speedup vs baseline: 1.2642x; 1.2642x over previous
//
#include <hip/hip_runtime.h>
#include <math.h>

#define B_SZ 16384
#define D_DIM 128
#define A_SZ 8192
#define K_SZ 64
#define L2_REG_F 0.25f
#define CONV_BLK 2048
#define NBLK 2048
#define GROUPS 32            // last-arriver: 32 groups x 64 blocks
#define CNT_STRIDE 32        // uints between counters (128 B, separate lines)

typedef float vfloat2 __attribute__((ext_vector_type(2)));

__device__ __forceinline__ float wave_reduce_sum(float v) {
    #pragma unroll
    for (int off = 32; off > 0; off >>= 1)
        v += __shfl_xor(v, off, 64);
    return v;
}

__device__ __forceinline__ float wave_reduce_max(float v) {
    #pragma unroll
    for (int off = 32; off > 0; off >>= 1)
        v = fmaxf(v, __shfl_xor(v, off, 64));
    return v;
}

__device__ __forceinline__ void dequant16(uint4 q, float4& o0, float4& o1,
                                          float4& o2, float4& o3) {
    vfloat2 f0 = __builtin_amdgcn_cvt_pk_f32_fp8(q.x, false);
    vfloat2 f1 = __builtin_amdgcn_cvt_pk_f32_fp8(q.x, true);
    vfloat2 f2 = __builtin_amdgcn_cvt_pk_f32_fp8(q.y, false);
    vfloat2 f3 = __builtin_amdgcn_cvt_pk_f32_fp8(q.y, true);
    vfloat2 f4 = __builtin_amdgcn_cvt_pk_f32_fp8(q.z, false);
    vfloat2 f5 = __builtin_amdgcn_cvt_pk_f32_fp8(q.z, true);
    vfloat2 f6 = __builtin_amdgcn_cvt_pk_f32_fp8(q.w, false);
    vfloat2 f7 = __builtin_amdgcn_cvt_pk_f32_fp8(q.w, true);
    o0 = make_float4(f0.x, f0.y, f1.x, f1.y);
    o1 = make_float4(f2.x, f2.y, f3.x, f3.y);
    o2 = make_float4(f4.x, f4.y, f5.x, f5.y);
    o3 = make_float4(f6.x, f6.y, f7.x, f7.y);
}

__device__ __forceinline__ float dot4(float4 a, float4 b) {
    return a.x * b.x + a.y * b.y + a.z * b.z + a.w * b.w;
}

// Pre-pass: fp32 -> fp8 e4m3 table (2 MB, L2-resident) + exact-fp32 l2-norm
// partials. Block 0 also zeroes the last-arriver counters (runs strictly
// before npair: stream/graph ordering + runtime inter-kernel coherence).
__global__ __launch_bounds__(256) void convert_kernel(const float* __restrict__ embed,
                                                      unsigned short* __restrict__ tab,
                                                      float* __restrict__ partial,
                                                      unsigned* __restrict__ cnt) {
    __shared__ float red[4];
    const int wave = threadIdx.x >> 6;
    const int lane = threadIdx.x & 63;
    const int gw   = blockIdx.x * 4 + wave;           // 0..8191
    if (blockIdx.x == 0) {
        for (int j = threadIdx.x; j < (GROUPS + 1) * CNT_STRIDE; j += 256)
            cnt[j] = 0u;
    }
    float acc = 0.f;
    #pragma unroll
    for (int r = 0; r < 2; ++r) {
        const int row = gw * 2 + r;
        const float2* rr = (const float2*)(embed + (size_t)row * D_DIM);
        float2 v = rr[lane];                          // elems 2*lane, 2*lane+1
        acc += sqrtf(wave_reduce_sum(v.x * v.x + v.y * v.y));  // exact fp32 norm
        unsigned pk = (unsigned)__builtin_amdgcn_cvt_pk_fp8_f32(v.x, v.y, 0, false);
        tab[(size_t)row * 64 + lane] = (unsigned short)pk;
    }
    if (lane == 0) red[wave] = acc * (L2_REG_F / (float)B_SZ); // pre-scaled
    __syncthreads();
    if (threadIdx.x == 0)
        partial[blockIdx.x] = red[0] + red[1] + red[2] + red[3];
}

// Main: one wave per anchor from the 2 MB L2-resident fp8 table. 8 lanes per
// negative row, all 8 gathers in flight. Finalize folded in: hierarchical
// last-arriver (only the ONE winning block pays the acquire/L2-invalidate).
__global__ __launch_bounds__(256) void npair_kernel(const unsigned short* __restrict__ tab,
                                                    const int* __restrict__ anc_ind,
                                                    const int* __restrict__ pos_ind,
                                                    const int* __restrict__ neg_ind,
                                                    float* __restrict__ partial,
                                                    unsigned* __restrict__ cnt,
                                                    float* __restrict__ out) {
    __shared__ float red[4];
    __shared__ int is_final;
    const int wave = threadIdx.x >> 6;
    const int lane = threadIdx.x & 63;
    const int i    = blockIdx.x * 4 + wave;           // anchor id 0..8191
    const int g = lane >> 3;   // row-in-pass 0..7
    const int c = lane & 7;    // 16B chunk 0..7 within a 128B row

    const int ai = anc_ind[i];
    const int pi = pos_ind[i];
    const int nid_all = neg_ind[(size_t)i * K_SZ + lane];  // coalesced 256B

    uint4 ua4 = ((const uint4*)(tab + (size_t)ai * 64))[c];
    uint4 up4 = ((const uint4*)(tab + (size_t)pi * 64))[c];

    int nidx[8];
    #pragma unroll
    for (int p = 0; p < 8; ++p)
        nidx[p] = __shfl(nid_all, p * 8 + g, 64);

    uint4 q[8];                 // all 8 gathers in flight (16 lines each)
    #pragma unroll
    for (int p = 0; p < 8; ++p)
        q[p] = ((const uint4*)(tab + (size_t)nidx[p] * 64))[c];

    float4 A0, A1, A2, A3;
    dequant16(ua4, A0, A1, A2, A3);
    float4 P0, P1, P2, P3;
    dequant16(up4, P0, P1, P2, P3);
    float ap = dot4(A0, P0) + dot4(A1, P1) + dot4(A2, P2) + dot4(A3, P3);
    ap += __shfl_xor(ap, 1, 64);
    ap += __shfl_xor(ap, 2, 64);
    ap += __shfl_xor(ap, 4, 64);

    float inner = 0.f;
    #pragma unroll
    for (int p = 0; p < 8; ++p) {
        float4 N0, N1, N2, N3;
        dequant16(q[p], N0, N1, N2, N3);
        float s = dot4(A0, N0) + dot4(A1, N1) + dot4(A2, N2) + dot4(A3, N3);
        s += __shfl_xor(s, 1, 64);
        s += __shfl_xor(s, 2, 64);
        s += __shfl_xor(s, 4, 64);
        if (c == p) inner = s;  // lane l keeps negative (l&7)*8 + (l>>3)
    }
    inner -= ap;                // permutation of the 64 inners: LSE-invariant

    float m  = wave_reduce_max(inner);
    float se = wave_reduce_sum(__expf(inner - m));
    float lse = m + __logf(se);
    float per = (lse > 0.f) ? lse + log1pf(__expf(-lse)) : log1pf(__expf(lse));

    if (lane == 0) red[wave] = per * (1.0f / (float)A_SZ);    // pre-scaled
    if (threadIdx.x == 0) is_final = 0;
    __syncthreads();
    if (threadIdx.x == 0) {
        partial[blockIdx.x] = red[0] + red[1] + red[2] + red[3];
        __threadfence();        // release this block's partial to device scope
        unsigned* gc   = cnt + (blockIdx.x >> 6) * CNT_STRIDE;
        unsigned* root = cnt + GROUPS * CNT_STRIDE;
        if (atomicAdd(gc, 1u) == 63u)
            if (atomicAdd(root, 1u) == GROUPS - 1)
                is_final = 1;   // all 2048 partials written & released
    }
    __syncthreads();
    if (is_final) {
        if (threadIdx.x == 0) __threadfence();  // acquire (one block only)
        __syncthreads();
        // reduce 4096 floats: [0..2047]=conv partials, [2048..4095]=np partials
        const float* allp = partial - CONV_BLK;
        float v = 0.f;
        #pragma unroll
        for (int j = 0; j < 16; ++j)
            v += allp[threadIdx.x + 256 * j];
        v = wave_reduce_sum(v);
        if (lane == 0) red[wave] = v;
        __syncthreads();
        if (threadIdx.x == 0)
            out[0] = red[0] + red[1] + red[2] + red[3];
    }
}

// ---- fp32 fallback (only if ws can't hold table+partials+counters) ----
__global__ __launch_bounds__(256) void f32_kernel(const float* __restrict__ embed,
                                                  const int* __restrict__ anc_ind,
                                                  const int* __restrict__ pos_ind,
                                                  const int* __restrict__ neg_ind,
                                                  float* __restrict__ partial) {
    __shared__ __align__(16) float a_lds[4][D_DIM];
    __shared__ float red[4];
    const int wave = threadIdx.x >> 6;
    const int lane = threadIdx.x & 63;
    const int gw   = blockIdx.x * 4 + wave;

    float acc_l2 = 0.f;
    #pragma unroll
    for (int r = 0; r < 2; ++r) {
        const int row = gw * 2 + r;
        const float2* rr = (const float2*)(embed + (size_t)row * D_DIM);
        float2 v = rr[lane];
        acc_l2 += sqrtf(wave_reduce_sum(v.x * v.x + v.y * v.y));
    }
    const int i  = gw;
    const int ai = anc_ind[i];
    const int pi = pos_ind[i];
    const int ni = neg_ind[(size_t)i * K_SZ + lane];
    const float2* ar = (const float2*)(embed + (size_t)ai * D_DIM);
    const float2* pr = (const float2*)(embed + (size_t)pi * D_DIM);
    float2 a2 = ar[lane];
    float2 p2 = pr[lane];
    a_lds[wave][2 * lane]     = a2.x;
    a_lds[wave][2 * lane + 1] = a2.y;
    float ap = wave_reduce_sum(a2.x * p2.x + a2.y * p2.y);
    const float4* nr = (const float4*)(embed + (size_t)ni * D_DIM);
    const float4* al = (const float4*)a_lds[wave];
    float s0 = 0.f, s1 = 0.f, s2 = 0.f, s3 = 0.f;
    #pragma unroll
    for (int j = 0; j < D_DIM / 4; j += 4) {
        float4 n0 = nr[j], n1 = nr[j + 1], n2 = nr[j + 2], n3 = nr[j + 3];
        float4 a0 = al[j], a1 = al[j + 1], a2v = al[j + 2], a3 = al[j + 3];
        s0 += dot4(a0, n0); s1 += dot4(a1, n1);
        s2 += dot4(a2v, n2); s3 += dot4(a3, n3);
    }
    float inner = (s0 + s1) + (s2 + s3) - ap;
    float m  = wave_reduce_max(inner);
    float se = wave_reduce_sum(__expf(inner - m));
    float lse = m + __logf(se);
    float per = (lse > 0.f) ? lse + log1pf(__expf(-lse)) : log1pf(__expf(lse));
    float combined = per * (1.0f / (float)A_SZ) + acc_l2 * (L2_REG_F / (float)B_SZ);
    if (lane == 0) red[wave] = combined;
    __syncthreads();
    if (threadIdx.x == 0)
        partial[blockIdx.x] = red[0] + red[1] + red[2] + red[3];
}

__global__ __launch_bounds__(256) void finalize_kernel(const float* __restrict__ partial,
                                                       int n, float* __restrict__ out) {
    __shared__ float red[4];
    const int wave = threadIdx.x >> 6;
    const int lane = threadIdx.x & 63;
    float v = 0.f;
    for (int j = threadIdx.x; j < n; j += 256) v += partial[j];
    v = wave_reduce_sum(v);
    if (lane == 0) red[wave] = v;
    __syncthreads();
    if (threadIdx.x == 0)
        out[0] = red[0] + red[1] + red[2] + red[3];
}

extern "C" void kernel_launch(void* const* d_in, const int* in_sizes, int n_in,
                              void* d_out, int out_size, void* d_ws, size_t ws_size,
                              hipStream_t stream) {
    const float* embed = (const float*)d_in[0];
    const int*   anc   = (const int*)d_in[1];
    const int*   pos   = (const int*)d_in[2];
    const int*   neg   = (const int*)d_in[3];
    float* out = (float*)d_out;

    const size_t tab_bytes  = (size_t)B_SZ * D_DIM;            // 2 MB fp8
    const size_t part_bytes = (size_t)(CONV_BLK + NBLK) * sizeof(float);
    const size_t cnt_bytes  = (size_t)(GROUPS + 1) * CNT_STRIDE * sizeof(unsigned);
    const size_t need = tab_bytes + part_bytes + cnt_bytes;

    if (ws_size >= need) {
        unsigned short* tab = (unsigned short*)d_ws;
        float* partial = (float*)((char*)d_ws + tab_bytes);    // [conv | npair]
        unsigned* cnt  = (unsigned*)((char*)partial + part_bytes);
        convert_kernel<<<CONV_BLK, 256, 0, stream>>>(embed, tab, partial, cnt);
        npair_kernel<<<NBLK, 256, 0, stream>>>(tab, anc, pos, neg,
                                               partial + CONV_BLK, cnt, out);
    } else {
        float* partial = (float*)d_ws;
        f32_kernel<<<2048, 256, 0, stream>>>(embed, anc, pos, neg, partial);
        finalize_kernel<<<1, 256, 0, stream>>>(partial, 2048, out);
    }
}

// Round 11
// 84.520 us; speedup vs baseline: 1.6712x; 1.3220x over previous
//
#include <hip/hip_runtime.h>
#include <math.h>

#define B_SZ 16384
#define D_DIM 128
#define A_SZ 8192
#define K_SZ 64
#define L2_REG_F 0.25f
#define GRID_BLKS 1024       // 4 blocks/CU x 256 CUs: co-resident (proven R9)
#define GROUPS 32            // hierarchical arrive: 32 groups x 32 blocks
#define BPG 32
#define CNT_STRIDE 32        // uints between counters (128 B apart)

typedef float vfloat2 __attribute__((ext_vector_type(2)));

__device__ __forceinline__ float wave_reduce_sum(float v) {
    #pragma unroll
    for (int off = 32; off > 0; off >>= 1)
        v += __shfl_xor(v, off, 64);
    return v;
}

__device__ __forceinline__ float wave_reduce_max(float v) {
    #pragma unroll
    for (int off = 32; off > 0; off >>= 1)
        v = fmaxf(v, __shfl_xor(v, off, 64));
    return v;
}

__device__ __forceinline__ void dequant16(uint4 q, float4& o0, float4& o1,
                                          float4& o2, float4& o3) {
    vfloat2 f0 = __builtin_amdgcn_cvt_pk_f32_fp8(q.x, false);
    vfloat2 f1 = __builtin_amdgcn_cvt_pk_f32_fp8(q.x, true);
    vfloat2 f2 = __builtin_amdgcn_cvt_pk_f32_fp8(q.y, false);
    vfloat2 f3 = __builtin_amdgcn_cvt_pk_f32_fp8(q.y, true);
    vfloat2 f4 = __builtin_amdgcn_cvt_pk_f32_fp8(q.z, false);
    vfloat2 f5 = __builtin_amdgcn_cvt_pk_f32_fp8(q.z, true);
    vfloat2 f6 = __builtin_amdgcn_cvt_pk_f32_fp8(q.w, false);
    vfloat2 f7 = __builtin_amdgcn_cvt_pk_f32_fp8(q.w, true);
    o0 = make_float4(f0.x, f0.y, f1.x, f1.y);
    o1 = make_float4(f2.x, f2.y, f3.x, f3.y);
    o2 = make_float4(f4.x, f4.y, f5.x, f5.y);
    o3 = make_float4(f6.x, f6.y, f7.x, f7.y);
}

__device__ __forceinline__ float dot4(float4 a, float4 b) {
    return a.x * b.x + a.y * b.y + a.z * b.z + a.w * b.w;
}

// per-anchor n-pair loss term; g = lane>>3 (row in pass), c = lane&7 (chunk)
__device__ __forceinline__ float anchor_loss(const unsigned char* __restrict__ tab,
                                             int nid_all, int ai, int pi,
                                             int g, int c, int lane) {
    uint4 ua4 = ((const uint4*)(tab + (size_t)ai * D_DIM))[c];  // 2-line bcast
    uint4 up4 = ((const uint4*)(tab + (size_t)pi * D_DIM))[c];

    int nidx[8];
    #pragma unroll
    for (int p = 0; p < 8; ++p)
        nidx[p] = __shfl(nid_all, p * 8 + g, 64);

    uint4 q[8];                  // all 8 gathers in flight (16 lines each)
    #pragma unroll
    for (int p = 0; p < 8; ++p)
        q[p] = ((const uint4*)(tab + (size_t)nidx[p] * D_DIM))[c];

    float4 A0, A1, A2, A3, P0, P1, P2, P3;
    dequant16(ua4, A0, A1, A2, A3);
    dequant16(up4, P0, P1, P2, P3);
    float ap = dot4(A0, P0) + dot4(A1, P1) + dot4(A2, P2) + dot4(A3, P3);
    ap += __shfl_xor(ap, 1, 64);
    ap += __shfl_xor(ap, 2, 64);
    ap += __shfl_xor(ap, 4, 64);

    float inner = 0.f;
    #pragma unroll
    for (int p = 0; p < 8; ++p) {
        float4 N0, N1, N2, N3;
        dequant16(q[p], N0, N1, N2, N3);
        float s = dot4(A0, N0) + dot4(A1, N1) + dot4(A2, N2) + dot4(A3, N3);
        s += __shfl_xor(s, 1, 64);
        s += __shfl_xor(s, 2, 64);
        s += __shfl_xor(s, 4, 64);
        if (c == p) inner = s;   // lane l keeps negative (l&7)*8 + (l>>3)
    }
    inner -= ap;                 // permutation of the 64 inners: LSE-invariant

    float m  = wave_reduce_max(inner);
    float se = wave_reduce_sum(__expf(inner - m));
    float lse = m + __logf(se);
    return (lse > 0.f) ? lse + log1pf(__expf(-lse)) : log1pf(__expf(lse));
}

// Single fused kernel, FENCE-FREE grid barrier:
//  - table & partial stores are agent-scope relaxed atomic stores (write-
//    through to device-coherent LLC; no dirty L2 -> no wbl2 needed)
//  - per-thread s_waitcnt(0) before arrival waits own store acks
//  - relaxed agent atomic counters; NO acquire (dispatch-start invalidate
//    guarantees no XCD holds stale tab/partial lines; readers miss to LLC)
__global__ __launch_bounds__(256, 4) void fused_kernel(
    const float* __restrict__ embed,
    const int* __restrict__ anc_ind,
    const int* __restrict__ pos_ind,
    const int* __restrict__ neg_ind,
    unsigned char* __restrict__ tab,      // 2 MB fp8 table, row stride 128 B
    float* __restrict__ partial,          // GRID_BLKS floats
    unsigned* __restrict__ cnt,           // counters, pre-zeroed by memset node
    float* __restrict__ out) {
    __shared__ float red[4];
    __shared__ int is_final;
    const int wave = threadIdx.x >> 6;
    const int lane = threadIdx.x & 63;
    const int blk  = blockIdx.x;
    const int w    = blk * 4 + wave;      // 0..4095

    // prefetch phase-2 indices NOW (independent of table; overlaps barrier)
    const int i0 = w * 2, i1 = w * 2 + 1; // anchors 0..8191
    const int nid0 = neg_ind[(size_t)i0 * K_SZ + lane];
    const int nid1 = neg_ind[(size_t)i1 * K_SZ + lane];
    const int ai0 = anc_ind[i0], pi0 = pos_ind[i0];
    const int ai1 = anc_ind[i1], pi1 = pos_ind[i1];

    // ---- phase 1: convert 4 rows/wave (16 lanes/row, 8 elems/lane) ----
    float acc_l2 = 0.f;
    {
        const int sub = lane >> 4;        // row within wave 0..3
        const int j   = lane & 15;        // 8-elem slot within row
        const int row = w * 4 + sub;      // covers 0..16383 exactly
        const float4* rp = (const float4*)(embed + (size_t)row * D_DIM + j * 8);
        float4 va = rp[0], vb = rp[1];
        float ss = dot4(va, va) + dot4(vb, vb);
        ss += __shfl_xor(ss, 1, 64);      // 16-lane group reduce
        ss += __shfl_xor(ss, 2, 64);
        ss += __shfl_xor(ss, 4, 64);
        ss += __shfl_xor(ss, 8, 64);
        if (j == 0) acc_l2 = sqrtf(ss);   // exact fp32 norm, 1 lane per row
        unsigned u0 = __builtin_amdgcn_cvt_pk_fp8_f32(va.x, va.y, 0, false);
        u0 = __builtin_amdgcn_cvt_pk_fp8_f32(va.z, va.w, u0, true);
        unsigned u1 = __builtin_amdgcn_cvt_pk_fp8_f32(vb.x, vb.y, 0, false);
        u1 = __builtin_amdgcn_cvt_pk_fp8_f32(vb.z, vb.w, u1, true);
        unsigned long long pk = ((unsigned long long)u1 << 32) | u0;
        // agent-scope write-through store: fresh data lands in coherent LLC
        __hip_atomic_store((unsigned long long*)(tab + (size_t)row * D_DIM) + j,
                           pk, __ATOMIC_RELAXED, __HIP_MEMORY_SCOPE_AGENT);
    }

    // ---- grid barrier (fence-free) ----
    __builtin_amdgcn_s_waitcnt(0);        // own write-through stores acked
    __syncthreads();
    if (threadIdx.x == 0) {
        unsigned* gc   = cnt + (blk >> 5) * CNT_STRIDE;
        unsigned* root = cnt + GROUPS * CNT_STRIDE;
        if (__hip_atomic_fetch_add(gc, 1u, __ATOMIC_RELAXED,
                                   __HIP_MEMORY_SCOPE_AGENT) == BPG - 1)
            __hip_atomic_fetch_add(root, 1u, __ATOMIC_RELAXED,
                                   __HIP_MEMORY_SCOPE_AGENT);
        int t = 0;
        while (__hip_atomic_load(root, __ATOMIC_RELAXED,
                                 __HIP_MEMORY_SCOPE_AGENT) < GROUPS) {
            __builtin_amdgcn_s_sleep(2);
            if (++t > (1 << 22)) break;   // safety valve: never hang
        }
    }
    __syncthreads();

    // ---- phase 2: 2 anchors per wave (plain cached gathers; L2 fills
    // from LLC which holds the fresh write-through table) ----
    const int g = lane >> 3;
    const int c = lane & 7;
    float acc_np = anchor_loss(tab, nid0, ai0, pi0, g, c, lane)
                 + anchor_loss(tab, nid1, ai1, pi1, g, c, lane);

    // ---- phase 3: block partial + last-arriver finalize (fence-free) ----
    float contrib = acc_l2 * (L2_REG_F / (float)B_SZ)
                  + ((lane == 0) ? acc_np * (1.0f / (float)A_SZ) : 0.f);
    contrib = wave_reduce_sum(contrib);
    if (lane == 0) red[wave] = contrib;
    if (threadIdx.x == 0) is_final = 0;
    __syncthreads();
    if (threadIdx.x == 0) {
        float bp = red[0] + red[1] + red[2] + red[3];
        __hip_atomic_store(&partial[blk], bp, __ATOMIC_RELAXED,
                           __HIP_MEMORY_SCOPE_AGENT);   // write-through
        __builtin_amdgcn_s_waitcnt(0);                  // store acked at LLC
        unsigned* gc2   = cnt + (GROUPS + 1 + (blk >> 5)) * CNT_STRIDE;
        unsigned* root2 = cnt + (2 * GROUPS + 1) * CNT_STRIDE;
        if (__hip_atomic_fetch_add(gc2, 1u, __ATOMIC_RELAXED,
                                   __HIP_MEMORY_SCOPE_AGENT) == BPG - 1)
            if (__hip_atomic_fetch_add(root2, 1u, __ATOMIC_RELAXED,
                                       __HIP_MEMORY_SCOPE_AGENT) == GROUPS - 1)
                is_final = 1;             // last arriver: all partials at LLC
    }
    __syncthreads();
    if (is_final) {
        float v = 0.f;
        #pragma unroll
        for (int k = 0; k < GRID_BLKS / 256; ++k)
            v += __hip_atomic_load(&partial[threadIdx.x + 256 * k],
                                   __ATOMIC_RELAXED, __HIP_MEMORY_SCOPE_AGENT);
        v = wave_reduce_sum(v);
        if (lane == 0) red[wave] = v;
        __syncthreads();
        if (threadIdx.x == 0)
            out[0] = red[0] + red[1] + red[2] + red[3];
    }
}

// ---- fp32 fallback (only if ws can't hold table+partials+counters) ----
__global__ __launch_bounds__(256) void f32_kernel(const float* __restrict__ embed,
                                                  const int* __restrict__ anc_ind,
                                                  const int* __restrict__ pos_ind,
                                                  const int* __restrict__ neg_ind,
                                                  float* __restrict__ partial) {
    __shared__ __align__(16) float a_lds[4][D_DIM];
    __shared__ float red[4];
    const int wave = threadIdx.x >> 6;
    const int lane = threadIdx.x & 63;
    const int gw   = blockIdx.x * 4 + wave;

    float acc_l2 = 0.f;
    #pragma unroll
    for (int r = 0; r < 2; ++r) {
        const int row = gw * 2 + r;
        const float2* rr = (const float2*)(embed + (size_t)row * D_DIM);
        float2 v = rr[lane];
        acc_l2 += sqrtf(wave_reduce_sum(v.x * v.x + v.y * v.y));
    }
    const int i  = gw;
    const int ai = anc_ind[i];
    const int pi = pos_ind[i];
    const int ni = neg_ind[(size_t)i * K_SZ + lane];
    const float2* ar = (const float2*)(embed + (size_t)ai * D_DIM);
    const float2* pr = (const float2*)(embed + (size_t)pi * D_DIM);
    float2 a2 = ar[lane];
    float2 p2 = pr[lane];
    a_lds[wave][2 * lane]     = a2.x;
    a_lds[wave][2 * lane + 1] = a2.y;
    float ap = wave_reduce_sum(a2.x * p2.x + a2.y * p2.y);
    const float4* nr = (const float4*)(embed + (size_t)ni * D_DIM);
    const float4* al = (const float4*)a_lds[wave];
    float s0 = 0.f, s1 = 0.f, s2 = 0.f, s3 = 0.f;
    #pragma unroll
    for (int j = 0; j < D_DIM / 4; j += 4) {
        float4 n0 = nr[j], n1 = nr[j + 1], n2 = nr[j + 2], n3 = nr[j + 3];
        float4 a0 = al[j], a1 = al[j + 1], a2v = al[j + 2], a3 = al[j + 3];
        s0 += dot4(a0, n0); s1 += dot4(a1, n1);
        s2 += dot4(a2v, n2); s3 += dot4(a3, n3);
    }
    float inner = (s0 + s1) + (s2 + s3) - ap;
    float m  = wave_reduce_max(inner);
    float se = wave_reduce_sum(__expf(inner - m));
    float lse = m + __logf(se);
    float per = (lse > 0.f) ? lse + log1pf(__expf(-lse)) : log1pf(__expf(lse));
    float combined = per * (1.0f / (float)A_SZ) + acc_l2 * (L2_REG_F / (float)B_SZ);
    if (lane == 0) red[wave] = combined;
    __syncthreads();
    if (threadIdx.x == 0)
        partial[blockIdx.x] = red[0] + red[1] + red[2] + red[3];
}

__global__ __launch_bounds__(256) void finalize_kernel(const float* __restrict__ partial,
                                                       int n, float* __restrict__ out) {
    __shared__ float red[4];
    const int wave = threadIdx.x >> 6;
    const int lane = threadIdx.x & 63;
    float v = 0.f;
    for (int j = threadIdx.x; j < n; j += 256) v += partial[j];
    v = wave_reduce_sum(v);
    if (lane == 0) red[wave] = v;
    __syncthreads();
    if (threadIdx.x == 0)
        out[0] = red[0] + red[1] + red[2] + red[3];
}

extern "C" void kernel_launch(void* const* d_in, const int* in_sizes, int n_in,
                              void* d_out, int out_size, void* d_ws, size_t ws_size,
                              hipStream_t stream) {
    const float* embed = (const float*)d_in[0];
    const int*   anc   = (const int*)d_in[1];
    const int*   pos   = (const int*)d_in[2];
    const int*   neg   = (const int*)d_in[3];
    float* out = (float*)d_out;

    const size_t tab_bytes  = (size_t)B_SZ * D_DIM;            // 2 MB fp8
    const size_t part_bytes = GRID_BLKS * sizeof(float);
    const size_t cnt_bytes  = (size_t)(2 * GROUPS + 2) * CNT_STRIDE * sizeof(unsigned);
    const size_t need = tab_bytes + part_bytes + cnt_bytes;

    if (ws_size >= need) {
        unsigned char* tab = (unsigned char*)d_ws;
        float* partial = (float*)(tab + tab_bytes);
        unsigned* cnt  = (unsigned*)((char*)partial + part_bytes);
        hipMemsetAsync(cnt, 0, cnt_bytes, stream);
        fused_kernel<<<GRID_BLKS, 256, 0, stream>>>(embed, anc, pos, neg,
                                                    tab, partial, cnt, out);
    } else {
        float* partial = (float*)d_ws;
        f32_kernel<<<2048, 256, 0, stream>>>(embed, anc, pos, neg, partial);
        finalize_kernel<<<1, 256, 0, stream>>>(partial, 2048, out);
    }
}